// Round 4
// baseline (98.285 us; speedup 1.0000x reference)
//
#include <hip/hip_runtime.h>
#include <hip/hip_cooperative_groups.h>

namespace cg = cooperative_groups;

// AggregationLoss. preds [32,6,256,256] f32, targets [32,2,256,256] i32.
// sim = preds[:,2:6]; text = targets[:,0]; kernel = targets[:,1]; MAX_T=16.
// Per sample: G[t] = mean of sim over kernel==t; per-pixel
// loss = log1p(max(||sim_p - G[text_p]|| - 0.5, 0)^2); per-instance mean over
// text==t for valid t (t>=1, k_cnt>0, t_cnt>0); output = mean over valid.
//
// R4: single cooperative kernel. Pass 1 accumulates segment stats in
// REGISTERS (R3 lesson: no LDS/global atomics), each thread caches its 16
// pixels (sim f32x4 + text id packed 8b) in registers across grid.sync(),
// so pass 2 reads nothing from global. 256 blocks x 512 threads = 1
// block/CU; __launch_bounds__(512,2) caps VGPR<=256 so cooperative
// co-residency (256 blocks) is guaranteed.

#define P_PIX 65536
#define NS 32
#define NB 8                   // blocks per sample; grid = 256
#define SP_F 96                // stats partial: kcnt[0..14] ksum[15..74] tcnt[75..89]
#define WS_STATS_OFF 0
#define WS_ISUM_OFF (NS * NB * SP_F)

__global__ __launch_bounds__(512, 2) void agg_fused_kernel(
        const float* __restrict__ preds,
        const int* __restrict__ targets,
        float* __restrict__ ws,
        float* __restrict__ out) {
    const int bid = blockIdx.x;
    const int s = bid >> 3;           // sample
    const int b = bid & (NB - 1);     // block within sample
    const int tid = threadIdx.x;
    const int lane = tid & 63;
    const int w = tid >> 6;           // wave id, 0..7

    const float* sim  = preds + (size_t)s * 6 * P_PIX + 2 * (size_t)P_PIX;
    const int*   text = targets + (size_t)s * 2 * P_PIX;
    const int*   kern = text + P_PIX;

    int   cnt[15];        // kcnt in low 16 bits, tcnt in high 16 bits
    float ksum[60];
    float simc[64];       // 16 pixels x 4 channels, register pixel cache
    int   tpack[4];       // 16 text ids, 8 bits each

    #pragma unroll
    for (int k = 0; k < 15; ++k) cnt[k] = 0;
    #pragma unroll
    for (int k = 0; k < 60; ++k) ksum[k] = 0.0f;

    // ---- pass 1: load + stats accumulate (keep pixels in regs) ----
    #pragma unroll
    for (int it = 0; it < 4; ++it) {
        const int p4 = b * 2048 + it * 512 + tid;      // float4 index
        const int4   tb4 = ((const int4*)text)[p4];
        const int4   kb4 = ((const int4*)kern)[p4];
        const float4 v0 = ((const float4*)(sim))[p4];
        const float4 v1 = ((const float4*)(sim + P_PIX))[p4];
        const float4 v2 = ((const float4*)(sim + 2 * P_PIX))[p4];
        const float4 v3 = ((const float4*)(sim + 3 * P_PIX))[p4];
        tpack[it] = tb4.x | (tb4.y << 8) | (tb4.z << 16) | (tb4.w << 24);
        const int tbv[4] = {tb4.x, tb4.y, tb4.z, tb4.w};
        const int kbv[4] = {kb4.x, kb4.y, kb4.z, kb4.w};
        const float a[4][4] = {{v0.x, v1.x, v2.x, v3.x}, {v0.y, v1.y, v2.y, v3.y},
                               {v0.z, v1.z, v2.z, v3.z}, {v0.w, v1.w, v2.w, v3.w}};
        #pragma unroll
        for (int j = 0; j < 4; ++j) {
            #pragma unroll
            for (int c = 0; c < 4; ++c) simc[it * 16 + j * 4 + c] = a[j][c];
            const int kb = kbv[j], tb = tbv[j];
            #pragma unroll
            for (int t = 1; t < 16; ++t) {
                cnt[t - 1] += ((kb == t) ? 1 : 0) + ((tb == t) ? 0x10000 : 0);
                #pragma unroll
                for (int c = 0; c < 4; ++c)
                    ksum[(t - 1) * 4 + c] += (kb == t) ? a[j][c] : 0.0f;
            }
        }
    }

    // wave reduce (75 values) to lane 0
    #pragma unroll
    for (int off = 32; off >= 1; off >>= 1) {
        #pragma unroll
        for (int k = 0; k < 15; ++k) cnt[k] += __shfl_down(cnt[k], off);
        #pragma unroll
        for (int k = 0; k < 60; ++k) ksum[k] += __shfl_down(ksum[k], off);
    }

    __shared__ int   wcnt[8][16];
    __shared__ float wsum[8][60];
    if (lane == 0) {
        #pragma unroll
        for (int k = 0; k < 15; ++k) wcnt[w][k] = cnt[k];
        #pragma unroll
        for (int k = 0; k < 60; ++k) wsum[w][k] = ksum[k];
    }
    __syncthreads();
    {
        float* part = ws + WS_STATS_OFF + (size_t)(s * NB + b) * SP_F;
        if (tid < 15) {
            int c = 0;
            #pragma unroll
            for (int q = 0; q < 8; ++q) c += wcnt[q][tid];
            part[tid] = (float)(c & 0xffff);
            part[75 + tid] = (float)(c >> 16);
        } else if (tid >= 64 && tid < 124) {
            const int k = tid - 64;
            float v = 0.0f;
            #pragma unroll
            for (int q = 0; q < 8; ++q) v += wsum[q][k];
            part[15 + k] = v;
        }
    }

    cg::this_grid().sync();

    // ---- G = ksum / max(kcnt,1), reduced over this sample's NB partials ----
    __shared__ float tmp[75];
    __shared__ __align__(16) float G[60];
    if (tid < 75) {
        const float* base = ws + WS_STATS_OFF + (size_t)s * NB * SP_F + tid;
        float v = 0.0f;
        #pragma unroll
        for (int pb = 0; pb < NB; ++pb) v += base[pb * SP_F];
        tmp[tid] = v;
    }
    __syncthreads();
    if (tid < 60) G[tid] = tmp[15 + tid] / fmaxf(tmp[tid >> 2], 1.0f);
    __syncthreads();

    // ---- pass 2: loss from the register pixel cache ----
    float isum[15];
    #pragma unroll
    for (int k = 0; k < 15; ++k) isum[k] = 0.0f;

    #pragma unroll
    for (int it = 0; it < 4; ++it) {
        #pragma unroll
        for (int j = 0; j < 4; ++j) {
            const int tb = (tpack[it] >> (8 * j)) & 0xff;
            const int gi = ((tb > 0) ? (tb - 1) : 0) * 4;   // tb==0 discarded below
            const float4 g = *(const float4*)&G[gi];
            const float d0 = simc[it * 16 + j * 4 + 0] - g.x;
            const float d1 = simc[it * 16 + j * 4 + 1] - g.y;
            const float d2 = simc[it * 16 + j * 4 + 2] - g.z;
            const float d3 = simc[it * 16 + j * 4 + 3] - g.w;
            const float dd = sqrtf(d0 * d0 + d1 * d1 + d2 * d2 + d3 * d3) - 0.5f;
            const float r = fmaxf(dd, 0.0f);
            const float lp = log1pf(r * r);
            #pragma unroll
            for (int t = 1; t < 16; ++t) isum[t - 1] += (tb == t) ? lp : 0.0f;
        }
    }

    #pragma unroll
    for (int off = 32; off >= 1; off >>= 1) {
        #pragma unroll
        for (int k = 0; k < 15; ++k) isum[k] += __shfl_down(isum[k], off);
    }

    __shared__ float iw[8][16];
    if (lane == 0) {
        #pragma unroll
        for (int k = 0; k < 15; ++k) iw[w][k] = isum[k];
    }
    __syncthreads();
    if (tid < 15) {
        float v = 0.0f;
        #pragma unroll
        for (int q = 0; q < 8; ++q) v += iw[q][tid];
        ws[WS_ISUM_OFF + (size_t)(s * NB + b) * 16 + tid] = v;
    }

    cg::this_grid().sync();

    // ---- finalize: one block per sample (b==0), lanes 0..15 ----
    if (b == 0 && tid < 16) {
        const int t = tid;            // bin index - 1; lane 15 inactive
        float kc = 0.0f, tc = 0.0f, is = 0.0f;
        if (t < 15) {
            #pragma unroll
            for (int pb = 0; pb < NB; ++pb) {
                const float* st = ws + WS_STATS_OFF + (size_t)(s * NB + pb) * SP_F;
                kc += st[t];
                tc += st[75 + t];
                is += ws[WS_ISUM_OFF + (size_t)(s * NB + pb) * 16 + t];
            }
        }
        const bool valid = (t < 15) && (kc > 0.0f) && (tc > 0.0f);
        float im = valid ? is / tc : 0.0f;
        float nv = valid ? 1.0f : 0.0f;
        #pragma unroll
        for (int m = 8; m >= 1; m >>= 1) {
            im += __shfl_xor(im, m, 16);
            nv += __shfl_xor(nv, m, 16);
        }
        if (t == 0) out[s] = (nv > 0.0f) ? (im / nv) : 0.0f;
    }
}

extern "C" void kernel_launch(void* const* d_in, const int* in_sizes, int n_in,
                              void* d_out, int out_size, void* d_ws, size_t ws_size,
                              hipStream_t stream) {
    const float* preds = (const float*)d_in[0];
    const int* targets = (const int*)d_in[1];
    float* out = (float*)d_out;
    float* ws = (float*)d_ws;

    void* args[] = {(void*)&preds, (void*)&targets, (void*)&ws, (void*)&out};
    hipLaunchCooperativeKernel((void*)agg_fused_kernel, dim3(NS * NB), dim3(512),
                               args, 0, stream);
}

// Round 5
// 67.310 us; speedup vs baseline: 1.4602x; 1.4602x over previous
//
#include <hip/hip_runtime.h>
#include <hip/hip_bf16.h>

// AggregationLoss. preds [32,6,256,256] f32, targets [32,2,256,256] i32.
// sim = preds[:,2:6]; text = targets[:,0]; kernel = targets[:,1]; MAX_T=16.
// Per sample: G[t] = mean of sim over kernel==t; per-pixel
// loss = log1p(max(||sim_p - G[text_p]|| - 0.5, 0)^2); per-instance mean over
// text==t for valid t (t>=1, k_cnt>0, t_cnt>0); output = mean over valid.
//
// R5: 3-kernel structure (R3) with two targeted fixes:
//  - counts via __popcll(__ballot()) -> SALU wave-uniform accumulators
//    (off the VALU, zero VGPR, zero reduce cost)
//  - ksum/isum block reduction via LDS transpose (stride-257 rows,
//    conflict-free) instead of 6-step shfl butterfly (450 bpermutes/wave)
// R4 lesson: do NOT cache pixels in regs across a grid sync (compiler won't
// keep them; pass-2 re-read is L3-served and nearly free).

#define P_PIX 65536
#define NS 32
#define NB 16              // blocks per sample; grid = 512 = 2 blocks/CU
#define SP_F 96            // stats partial stride: kcnt[0..14] ksum[15..74] tcnt[75..89]
#define WS_STATS_OFF 0
#define WS_ISUM_OFF (NS * NB * SP_F)   // isum partials: [NS][NB][16]

__global__ __launch_bounds__(256, 2) void agg_stats_kernel(
        const float* __restrict__ preds,
        const int* __restrict__ targets,
        float* __restrict__ ws) {
    const int s = blockIdx.y;
    const int b = blockIdx.x;
    const int tid = threadIdx.x;
    const int lane = tid & 63;
    const int w = tid >> 6;

    float ksum[60];
    #pragma unroll
    for (int k = 0; k < 60; ++k) ksum[k] = 0.0f;
    unsigned int cnt[15];          // kcnt low16 | tcnt high16, wave-uniform
    #pragma unroll
    for (int k = 0; k < 15; ++k) cnt[k] = 0u;

    const float* sim  = preds + (size_t)s * 6 * P_PIX + 2 * (size_t)P_PIX;
    const int*   text = targets + (size_t)s * 2 * P_PIX;
    const int*   kern = text + P_PIX;

    #pragma unroll
    for (int it = 0; it < 4; ++it) {
        const int p4 = b * 1024 + it * 256 + tid;   // float4 index
        const int4   tb4 = ((const int4*)text)[p4];
        const int4   kb4 = ((const int4*)kern)[p4];
        const float4 v0 = ((const float4*)(sim))[p4];
        const float4 v1 = ((const float4*)(sim + P_PIX))[p4];
        const float4 v2 = ((const float4*)(sim + 2 * P_PIX))[p4];
        const float4 v3 = ((const float4*)(sim + 3 * P_PIX))[p4];
        const int tbv[4] = {tb4.x, tb4.y, tb4.z, tb4.w};
        const int kbv[4] = {kb4.x, kb4.y, kb4.z, kb4.w};
        const float a[4][4] = {{v0.x, v1.x, v2.x, v3.x}, {v0.y, v1.y, v2.y, v3.y},
                               {v0.z, v1.z, v2.z, v3.z}, {v0.w, v1.w, v2.w, v3.w}};
        #pragma unroll
        for (int j = 0; j < 4; ++j) {
            const int kb = kbv[j], tb = tbv[j];
            #pragma unroll
            for (int t = 1; t < 16; ++t) {
                const bool pk = (kb == t);
                const unsigned int ck = (unsigned int)__popcll(__ballot(pk));
                const unsigned int ct = (unsigned int)__popcll(__ballot(tb == t));
                cnt[t - 1] += ck + (ct << 16);
                const float m = pk ? 1.0f : 0.0f;
                #pragma unroll
                for (int c = 0; c < 4; ++c)
                    ksum[(t - 1) * 4 + c] = fmaf(m, a[j][c], ksum[(t - 1) * 4 + c]);
            }
        }
    }

    // ---- block reduce: counts via LDS (wave-uniform), ksum via transpose ----
    __shared__ unsigned int scnt[4][15];
    __shared__ float tl[60 * 257];        // 61.7 KB, stride 257 (odd) -> no conflicts
    __shared__ float red2[240];
    if (lane == 0) {
        #pragma unroll
        for (int k = 0; k < 15; ++k) scnt[w][k] = cnt[k];
    }
    #pragma unroll
    for (int k = 0; k < 60; ++k) tl[k * 257 + tid] = ksum[k];
    __syncthreads();

    if (tid < 240) {
        const int g = tid >> 6;           // NOTE: tid<240 -> g in 0..3, c below
        const int c = tid - g * 60 - ((tid >= 60 && g == 0) ? 0 : 0);
        // simpler exact mapping:
        const int gg = tid / 60;
        const int cc = tid - gg * 60;
        const float* p = &tl[cc * 257 + gg * 64];
        float v0 = 0.0f, v1 = 0.0f, v2 = 0.0f, v3 = 0.0f;
        #pragma unroll
        for (int i = 0; i < 64; i += 4) {
            v0 += p[i]; v1 += p[i + 1]; v2 += p[i + 2]; v3 += p[i + 3];
        }
        red2[cc * 4 + gg] = (v0 + v1) + (v2 + v3);
        (void)g; (void)c;
    }
    __syncthreads();

    float* part = ws + WS_STATS_OFF + (size_t)(s * NB + b) * SP_F;
    if (tid < 60) {
        part[15 + tid] = (red2[tid * 4] + red2[tid * 4 + 1]) +
                         (red2[tid * 4 + 2] + red2[tid * 4 + 3]);
    } else if (tid >= 64 && tid < 79) {
        const int k = tid - 64;
        const unsigned int ctot = scnt[0][k] + scnt[1][k] + scnt[2][k] + scnt[3][k];
        part[k] = (float)(ctot & 0xffffu);
        part[75 + k] = (float)(ctot >> 16);
    }
}

__global__ __launch_bounds__(256, 2) void agg_loss_kernel(
        const float* __restrict__ preds,
        const int* __restrict__ targets,
        float* __restrict__ ws) {
    const int s = blockIdx.y;
    const int b = blockIdx.x;
    const int tid = threadIdx.x;

    __shared__ float tmp[90];
    __shared__ __align__(16) float G4[16][4];   // G4[0] = 0 (background dummy)
    if (tid < 90) {
        const float* base = ws + WS_STATS_OFF + (size_t)s * NB * SP_F + tid;
        float v = 0.0f;
        #pragma unroll
        for (int pb = 0; pb < NB; ++pb) v += base[pb * SP_F];
        tmp[tid] = v;
    }
    __syncthreads();
    if (tid < 60) G4[1 + (tid >> 2)][tid & 3] = tmp[15 + tid] / fmaxf(tmp[tid >> 2], 1.0f);
    if (tid >= 64 && tid < 68) G4[0][tid - 64] = 0.0f;
    __syncthreads();

    float isum[15];
    #pragma unroll
    for (int k = 0; k < 15; ++k) isum[k] = 0.0f;

    const float* sim  = preds + (size_t)s * 6 * P_PIX + 2 * (size_t)P_PIX;
    const int*   text = targets + (size_t)s * 2 * P_PIX;

    #pragma unroll
    for (int it = 0; it < 4; ++it) {
        const int p4 = b * 1024 + it * 256 + tid;
        const int4   tb4 = ((const int4*)text)[p4];
        const float4 v0 = ((const float4*)(sim))[p4];
        const float4 v1 = ((const float4*)(sim + P_PIX))[p4];
        const float4 v2 = ((const float4*)(sim + 2 * P_PIX))[p4];
        const float4 v3 = ((const float4*)(sim + 3 * P_PIX))[p4];
        const int tbv[4] = {tb4.x, tb4.y, tb4.z, tb4.w};
        const float a[4][4] = {{v0.x, v1.x, v2.x, v3.x}, {v0.y, v1.y, v2.y, v3.y},
                               {v0.z, v1.z, v2.z, v3.z}, {v0.w, v1.w, v2.w, v3.w}};
        #pragma unroll
        for (int j = 0; j < 4; ++j) {
            const int tb = tbv[j];
            const float4 g = *(const float4*)G4[tb];
            const float d0 = a[j][0] - g.x;
            const float d1 = a[j][1] - g.y;
            const float d2 = a[j][2] - g.z;
            const float d3 = a[j][3] - g.w;
            const float dd = sqrtf(d0 * d0 + d1 * d1 + d2 * d2 + d3 * d3) - 0.5f;
            const float r = fmaxf(dd, 0.0f);
            const float lp = log1pf(r * r);
            #pragma unroll
            for (int t = 1; t < 16; ++t) isum[t - 1] += (tb == t) ? lp : 0.0f;
        }
    }

    // ---- block reduce isum via LDS transpose ----
    __shared__ float tl2[15 * 257];      // 15.4 KB
    __shared__ float red2b[60];
    #pragma unroll
    for (int k = 0; k < 15; ++k) tl2[k * 257 + tid] = isum[k];
    __syncthreads();
    if (tid < 60) {
        const int c = tid >> 2, g = tid & 3;
        const float* p = &tl2[c * 257 + g * 64];
        float v0 = 0.0f, v1 = 0.0f, v2 = 0.0f, v3 = 0.0f;
        #pragma unroll
        for (int i = 0; i < 64; i += 4) {
            v0 += p[i]; v1 += p[i + 1]; v2 += p[i + 2]; v3 += p[i + 3];
        }
        red2b[tid] = (v0 + v1) + (v2 + v3);
    }
    __syncthreads();
    if (tid < 15) {
        ws[WS_ISUM_OFF + (size_t)(s * NB + b) * 16 + tid] =
            (red2b[tid * 4] + red2b[tid * 4 + 1]) +
            (red2b[tid * 4 + 2] + red2b[tid * 4 + 3]);
    }
}

__global__ __launch_bounds__(512) void agg_finalize_kernel(
        const float* __restrict__ ws, float* __restrict__ out) {
    const int tid = threadIdx.x;       // 512 = 32 samples * 16 lanes
    const int s = tid >> 4;
    const int t = tid & 15;            // bin index - 1; lane 15 inactive
    float kc = 0.0f, tc = 0.0f, is = 0.0f;
    if (t < 15) {
        #pragma unroll 4
        for (int pb = 0; pb < NB; ++pb) {
            const float* st = ws + WS_STATS_OFF + (size_t)(s * NB + pb) * SP_F;
            kc += st[t];
            tc += st[75 + t];
            is += ws[WS_ISUM_OFF + (size_t)(s * NB + pb) * 16 + t];
        }
    }
    const bool valid = (t < 15) && (kc > 0.0f) && (tc > 0.0f);
    float im = valid ? is / tc : 0.0f;
    float nv = valid ? 1.0f : 0.0f;
    #pragma unroll
    for (int m = 8; m >= 1; m >>= 1) {
        im += __shfl_xor(im, m, 16);
        nv += __shfl_xor(nv, m, 16);
    }
    if (t == 0) out[s] = (nv > 0.0f) ? (im / nv) : 0.0f;
}

extern "C" void kernel_launch(void* const* d_in, const int* in_sizes, int n_in,
                              void* d_out, int out_size, void* d_ws, size_t ws_size,
                              hipStream_t stream) {
    const float* preds = (const float*)d_in[0];
    const int* targets = (const int*)d_in[1];
    float* out = (float*)d_out;
    float* ws = (float*)d_ws;

    dim3 grid(NB, NS);
    agg_stats_kernel<<<grid, 256, 0, stream>>>(preds, targets, ws);
    agg_loss_kernel<<<grid, 256, 0, stream>>>(preds, targets, ws);
    agg_finalize_kernel<<<1, 512, 0, stream>>>(ws, out);
}